// Round 14
// baseline (194.589 us; speedup 1.0000x reference)
//
#include <hip/hip_runtime.h>

// Problem constants
#define BB  16
#define JJ  32
#define HH  512
#define WW  512
#define KK  9
#define PAD 3
#define OH  510
#define OW  510

// Full-width implicit GEMM (r12 base: block = [16 j][4 rows][512 px],
// XCD swizzle, parity-split k-mapping). ONE change vs r12: accumulators
// persist across all 4 rows (acc[4][8]); the D-buffer, store phases and
// ALL main-loop barriers are gone. The block's entire 130KB write set is
// issued as ONE register->global burst in plane-major order, so L2 holds
// all 4 rows x 16 planes simultaneously and can drain plane-sorted 8160B
// runs to DRAM (r12 delivered 2040B fragments interleaved across 16
// planes -> 3.7 TB/s effective write BW vs 6.6 memset).
#define RROWS  4
#define NRAW   12
#define IN_DW  268                  // dwords per input row (264 used + pad)
#define IN_PITCH_B (IN_DW * 4)      // 1072
#define IN_BYTES (NRAW * IN_PITCH_B)   // 12864

// raw f32 weights [16 j][10 u][20 v'] (v' = v+1, zero-padded)
#define WRAW_OFF IN_BYTES
#define LDS_BYTES (WRAW_OFF + 16 * 200 * 4)   // 25664 B

typedef __bf16 bf16x8 __attribute__((ext_vector_type(8)));
typedef float  f32x4  __attribute__((ext_vector_type(4)));

__device__ __forceinline__ unsigned pack2bf(float a, float b) {
    unsigned ua = __float_as_uint(a) + 0x8000u;
    unsigned ub = __float_as_uint(b) + 0x8000u;
    return (ua >> 16) | (ub & 0xFFFF0000u);
}

__global__ __launch_bounds__(256, 2)
void conv_mfma_kernel(const float* __restrict__ in,
                      const float* __restrict__ wgt,
                      float* __restrict__ out) {
    __shared__ __align__(16) char lds[LDS_BYTES];

    const int tid  = threadIdx.x;
    const int lane = tid & 63;
    const int w    = tid >> 6;     // wave 0..3
    const int c    = lane & 15;
    const int q    = lane >> 4;
    const int g    = q >> 1;
    const int h    = q & 1;
    const int par  = w >> 1;       // x parity handled by this wave

    // ---- XCD swizzle: consecutive same-XCD slots = consecutive y-tiles ----
    const int id  = blockIdx.x;            // 0..4095
    const int xcd = id & 7;
    const int wk  = xcd * 512 + (id >> 3); // bijective
    const int yt  = wk & 127;              // 0..127
    const int p   = wk >> 7;               // 0..31
    const int jg  = p & 1;
    const int bi  = p >> 1;
    const int y0  = yt * RROWS;

    // ---- zero raw-weight region (16 j x 200 f32 = 12800 B) ----
    {
        const uint4 z = make_uint4(0u, 0u, 0u, 0u);
        for (int idx = tid; idx < 800; idx += 256)
            *(uint4*)(lds + WRAW_OFF + idx * 16) = z;
    }
    __syncthreads();

    // ---- fill raw weights [16 j][10 u][20 v'], v'=v+1; stage input rows ----
    float* rawF = (float*)(lds + WRAW_OFF);
    const float* wB = wgt + (size_t)(bi * JJ + jg * 16) * (KK * KK);
    for (int idx = tid; idx < 16 * 81; idx += 256) {
        const int j   = idx / 81;
        const int rem = idx - j * 81;
        const int u   = rem / 9;
        const int v   = rem - u * 9;
        rawF[j * 200 + u * 20 + v + 1] = wB[idx];
    }

    // stage 12 full-width input rows as bf16 (elements -4..523)
    const float* inB = in + (size_t)bi * (HH * WW);
    #pragma unroll 1
    for (int idx = tid; idx < NRAW * 66; idx += 256) {
        const int rr = idx / 66;
        const int m  = idx - rr * 66;       // chunk: elements 8m-4 .. 8m+3
        const int gr = y0 - PAD + rr;
        float el[8];
        if ((unsigned)gr < (unsigned)HH) {
            const float* rp = inB + gr * WW + 8 * m - 4;
            if (m >= 1 && m <= 63) {
                const float4 a = *(const float4*)rp;
                const float4 b = *(const float4*)(rp + 4);
                el[0]=a.x; el[1]=a.y; el[2]=a.z; el[3]=a.w;
                el[4]=b.x; el[5]=b.y; el[6]=b.z; el[7]=b.w;
            } else {
                #pragma unroll
                for (int t = 0; t < 8; ++t) {
                    const int gx = 8 * m - 4 + t;
                    el[t] = ((unsigned)gx < (unsigned)WW) ? rp[t] : 0.f;
                }
            }
        } else {
            #pragma unroll
            for (int t = 0; t < 8; ++t) el[t] = 0.f;
        }
        *(uint4*)(lds + rr * IN_PITCH_B + m * 16) =
            make_uint4(pack2bf(el[0], el[1]), pack2bf(el[2], el[3]),
                       pack2bf(el[4], el[5]), pack2bf(el[6], el[7]));
    }
    __syncthreads();

    // ---- A fragments to registers: afrag[s], j = c, v = 8h + e - 1 + par ----
    bf16x8 afrag[5];
    #pragma unroll
    for (int s = 0; s < 5; ++s) {
        const int u = 2 * s + g;            // 0..9 (u=9 row stays zero)
        const int base = c * 200 + u * 20 + 8 * h + par;  // v'=v+1 folded in
        float wv[8];
        #pragma unroll
        for (int e = 0; e < 8; ++e) wv[e] = rawF[base + e];
        const uint4 pk = make_uint4(pack2bf(wv[0], wv[1]), pack2bf(wv[2], wv[3]),
                                    pack2bf(wv[4], wv[5]), pack2bf(wv[6], wv[7]));
        afrag[s] = __builtin_bit_cast(bf16x8, pk);
    }

    // ---- compute: all 4 rows, accumulators persistent, NO barriers ----
    const uint* L = (const uint*)lds;
    const int dwl = c + par + 4 * h + 128 * (w & 1);

    f32x4 acc[RROWS][8];
    #pragma unroll
    for (int r = 0; r < RROWS; ++r)
        #pragma unroll
        for (int i = 0; i < 8; ++i)
            acc[r][i] = (f32x4){0.f, 0.f, 0.f, 0.f};

    #pragma unroll
    for (int r = 0; r < RROWS; ++r) {
        #pragma unroll
        for (int s = 0; s < 5; ++s) {
            int u = 2 * s + g;
            if (u > 8) u = 0;               // afrag[s]==0 there; finite B ok
            const int rowdw = (r + u) * IN_DW + dwl;
            #pragma unroll
            for (int i = 0; i < 8; ++i) {
                const int d = rowdw + 16 * i;
                const uint4 bv = make_uint4(L[d], L[d + 1], L[d + 2], L[d + 3]);
                acc[r][i] = __builtin_amdgcn_mfma_f32_16x16x32_bf16(
                                afrag[s], __builtin_bit_cast(bf16x8, bv),
                                acc[r][i], 0, 0, 0);
            }
        }
    }

    // ---- single direct store burst, plane-major (rg -> r -> i) ----
    const int xb = 256 * (w & 1) + 2 * c + par;
    const size_t plane = (size_t)OH * OW;
    float* outB = out + (size_t)(bi * JJ + jg * 16) * plane;

    #pragma unroll
    for (int rg = 0; rg < 4; ++rg) {
        const int jl = q * 4 + rg;
        float* opl = outB + (size_t)jl * plane;
        #pragma unroll
        for (int r = 0; r < RROWS; ++r) {
            const int y = y0 + r;
            if (y < OH) {
                float* orow = opl + (size_t)y * OW;
                #pragma unroll
                for (int i = 0; i < 8; ++i) {
                    const int px = xb + 32 * i;
                    if (px < OW) orow[px] = acc[r][i][rg];
                }
            }
        }
    }
}

extern "C" void kernel_launch(void* const* d_in, const int* in_sizes, int n_in,
                              void* d_out, int out_size, void* d_ws, size_t ws_size,
                              hipStream_t stream) {
    const float* inp = (const float*)d_in[0];   // [16,1,512,512] f32
    const float* wgt = (const float*)d_in[1];   // [16,32,9,9]    f32
    float* out = (float*)d_out;                 // [16,32,510,510] f32

    conv_mfma_kernel<<<dim3(4096), 256, 0, stream>>>(inp, wgt, out);
}

// Round 15
// 149.609 us; speedup vs baseline: 1.3007x; 1.3007x over previous
//
#include <hip/hip_runtime.h>

// Problem constants
#define BB  16
#define JJ  32
#define HH  512
#define WW  512
#define KK  9
#define PAD 3
#define OH  510
#define OW  510

// Full-width implicit GEMM (r12 base: block=[16 j][4 rows][512 px], XCD
// swizzle, parity-split k-mapping). Change vs r12: accumulators persist
// across all 4 rows; stores happen in 4 j-group phases. Phase p: lanes
// q==p dump acc into D [4 j][4 rows][516]; barrier; each WAVE stores one
// plane sub-block as 16 consecutive 512B float2-insts = 8160B MONOTONIC
// CONTIGUOUS (r12 delivered 2040B fragments interleaved across 16 plane
// streams). Keeps r12's per-inst coalescing (r14 lesson) while 4x-ing
// program-order run length (r10/r12 lever).
#define RROWS  4
#define NRAW   12
#define IN_DW  268                  // dwords per input row (264 used + pad)
#define IN_PITCH_B (IN_DW * 4)      // 1072
#define IN_BYTES (NRAW * IN_PITCH_B)   // 12864

#define D_RP   516                  // f32 per (j,row)
#define DBUF_OFF IN_BYTES
#define LDS_BYTES (DBUF_OFF + 16 * D_RP * 4)   // 12864 + 33024 = 45888

// raw f32 weights [16 j][10 u][20 v'] (v'=v+1, zero-padded), union with D
#define WRAW_OFF DBUF_OFF           // 12800 B <= 33024 (D region)

typedef __bf16 bf16x8 __attribute__((ext_vector_type(8)));
typedef float  f32x4  __attribute__((ext_vector_type(4)));

__device__ __forceinline__ unsigned pack2bf(float a, float b) {
    unsigned ua = __float_as_uint(a) + 0x8000u;
    unsigned ub = __float_as_uint(b) + 0x8000u;
    return (ua >> 16) | (ub & 0xFFFF0000u);
}

// barrier waiting only on LDS ops -- global stores stay in flight (r9+)
__device__ __forceinline__ void barrier_lds_only() {
    asm volatile("s_waitcnt lgkmcnt(0)" ::: "memory");
    __builtin_amdgcn_s_barrier();
}

__global__ __launch_bounds__(256, 2)
void conv_mfma_kernel(const float* __restrict__ in,
                      const float* __restrict__ wgt,
                      float* __restrict__ out) {
    __shared__ __align__(16) char lds[LDS_BYTES];

    const int tid  = threadIdx.x;
    const int lane = tid & 63;
    const int w    = tid >> 6;     // wave 0..3
    const int c    = lane & 15;
    const int q    = lane >> 4;
    const int g    = q >> 1;
    const int h    = q & 1;
    const int par  = w >> 1;       // x parity handled by this wave

    // ---- XCD swizzle: consecutive same-XCD slots = consecutive y-tiles ----
    const int id  = blockIdx.x;            // 0..4095
    const int xcd = id & 7;
    const int wk  = xcd * 512 + (id >> 3); // bijective
    const int yt  = wk & 127;              // 0..127
    const int pp  = wk >> 7;               // 0..31
    const int jg  = pp & 1;
    const int bi  = pp >> 1;
    const int y0  = yt * RROWS;

    // ---- zero raw-weight region (16 j x 200 f32 = 12800 B) ----
    {
        const uint4 z = make_uint4(0u, 0u, 0u, 0u);
        for (int idx = tid; idx < 800; idx += 256)
            *(uint4*)(lds + WRAW_OFF + idx * 16) = z;
    }
    __syncthreads();

    // ---- fill raw weights [16 j][10 u][20 v'], v' = v+1 ----
    float* rawF = (float*)(lds + WRAW_OFF);
    const float* wB = wgt + (size_t)(bi * JJ + jg * 16) * (KK * KK);
    for (int idx = tid; idx < 16 * 81; idx += 256) {
        const int j   = idx / 81;
        const int rem = idx - j * 81;
        const int u   = rem / 9;
        const int v   = rem - u * 9;
        rawF[j * 200 + u * 20 + v + 1] = wB[idx];
    }
    __syncthreads();

    // ---- A fragments: afrag[s], j = c, v = 8h + e - 1 + par ----
    // (read BEFORE the staging barrier: orders all afrag reads before any
    //  later D-buffer write that aliases the weight region)
    bf16x8 afrag[5];
    #pragma unroll
    for (int s = 0; s < 5; ++s) {
        const int u = 2 * s + g;            // 0..9 (u=9 row stays zero)
        const int base = c * 200 + u * 20 + 8 * h + par;  // v'=v+1 folded in
        float wv[8];
        #pragma unroll
        for (int e = 0; e < 8; ++e) wv[e] = rawF[base + e];
        const uint4 pk = make_uint4(pack2bf(wv[0], wv[1]), pack2bf(wv[2], wv[3]),
                                    pack2bf(wv[4], wv[5]), pack2bf(wv[6], wv[7]));
        afrag[s] = __builtin_bit_cast(bf16x8, pk);
    }

    // ---- stage 12 full-width input rows as bf16 (elements -4..523) ----
    const float* inB = in + (size_t)bi * (HH * WW);
    #pragma unroll 1
    for (int idx = tid; idx < NRAW * 66; idx += 256) {
        const int rr = idx / 66;
        const int m  = idx - rr * 66;       // chunk: elements 8m-4 .. 8m+3
        const int gr = y0 - PAD + rr;
        float el[8];
        if ((unsigned)gr < (unsigned)HH) {
            const float* rp = inB + gr * WW + 8 * m - 4;
            if (m >= 1 && m <= 63) {
                const float4 a = *(const float4*)rp;
                const float4 b = *(const float4*)(rp + 4);
                el[0]=a.x; el[1]=a.y; el[2]=a.z; el[3]=a.w;
                el[4]=b.x; el[5]=b.y; el[6]=b.z; el[7]=b.w;
            } else {
                #pragma unroll
                for (int t = 0; t < 8; ++t) {
                    const int gx = 8 * m - 4 + t;
                    el[t] = ((unsigned)gx < (unsigned)WW) ? rp[t] : 0.f;
                }
            }
        } else {
            #pragma unroll
            for (int t = 0; t < 8; ++t) el[t] = 0.f;
        }
        *(uint4*)(lds + rr * IN_PITCH_B + m * 16) =
            make_uint4(pack2bf(el[0], el[1]), pack2bf(el[2], el[3]),
                       pack2bf(el[4], el[5]), pack2bf(el[6], el[7]));
    }
    __syncthreads();   // afrag read + input staged; D region now free

    // ---- compute: all 4 rows, accumulators persistent, no barriers ----
    const uint* L = (const uint*)lds;
    const int dwl = c + par + 4 * h + 128 * (w & 1);

    f32x4 acc[RROWS][8];
    #pragma unroll
    for (int r = 0; r < RROWS; ++r)
        #pragma unroll
        for (int i = 0; i < 8; ++i)
            acc[r][i] = (f32x4){0.f, 0.f, 0.f, 0.f};

    #pragma unroll
    for (int r = 0; r < RROWS; ++r) {
        #pragma unroll
        for (int s = 0; s < 5; ++s) {
            int u = 2 * s + g;
            if (u > 8) u = 0;               // afrag[s]==0 there; finite B ok
            const int rowdw = (r + u) * IN_DW + dwl;
            #pragma unroll
            for (int i = 0; i < 8; ++i) {
                const int d = rowdw + 16 * i;
                const uint4 bv = make_uint4(L[d], L[d + 1], L[d + 2], L[d + 3]);
                acc[r][i] = __builtin_amdgcn_mfma_f32_16x16x32_bf16(
                                afrag[s], __builtin_bit_cast(bf16x8, bv),
                                acc[r][i], 0, 0, 0);
            }
        }
    }

    // ---- 4 j-group store phases: 8160B contiguous per wave per phase ----
    float* D = (float*)(lds + DBUF_OFF);
    const int xb = 256 * (w & 1) + 2 * c + par;
    const size_t plane = (size_t)OH * OW;
    float* outB = out + (size_t)(bi * JJ + jg * 16) * plane;

    #pragma unroll 1
    for (int p = 0; p < 4; ++p) {
        // lanes owning j-group p dump their acc (all rg, rows, subtiles)
        if (q == p) {
            #pragma unroll
            for (int rg = 0; rg < 4; ++rg)
                #pragma unroll
                for (int r = 0; r < RROWS; ++r)
                    #pragma unroll
                    for (int i = 0; i < 8; ++i)
                        D[(rg * RROWS + r) * D_RP + xb + 32 * i] = acc[r][i][rg];
        }
        barrier_lds_only();

        // wave w stores plane (p*4 + w): rows y0..y0+3 are CONTIGUOUS bytes
        const int jl = p * 4 + w;
        float* opl = outB + (size_t)jl * plane + (size_t)y0 * OW;
        #pragma unroll
        for (int r = 0; r < RROWS; ++r) {
            if (y0 + r < OH) {
                #pragma unroll
                for (int seg = 0; seg < 4; ++seg) {
                    const int px = seg * 128 + 2 * lane;
                    if (px + 1 < OW)
                        *(float2*)(opl + (size_t)r * OW + px) =
                            *(const float2*)&D[(w * RROWS + r) * D_RP + px];
                }
            }
        }
        barrier_lds_only();   // D reads done; next phase may overwrite D
    }
}

extern "C" void kernel_launch(void* const* d_in, const int* in_sizes, int n_in,
                              void* d_out, int out_size, void* d_ws, size_t ws_size,
                              hipStream_t stream) {
    const float* inp = (const float*)d_in[0];   // [16,1,512,512] f32
    const float* wgt = (const float*)d_in[1];   // [16,32,9,9]    f32
    float* out = (float*)d_out;                 // [16,32,510,510] f32

    conv_mfma_kernel<<<dim3(4096), 256, 0, stream>>>(inp, wgt, out);
}